// Round 7
// baseline (36.455 us; speedup 1.0000x reference)
//
#include <hip/hip_runtime.h>
#include <hip/hip_bf16.h>

#define NG 128
#define NT 16

// ws float layout (all tables contiguous, 7680 floats total):
//   gtab  [128][8]  : {betaT0..3, phi, maskbits(as float bits), 0, 0} (1024 f)
//   mdemd [128][16][2] : {md, exp(md)} interleaved                    (4096 f)
//   lgtab [128][20] : gammaln(phi+k)-gammaln(1+k)-gammaln(phi)+phi*ln(phi) (2560 f)
#define GTAB_OFF 0
#define MDEMD_OFF 1024
#define LGTAB_OFF 5120
#define TAB_FLOATS 7680
#define LN2 0.6931471805599453f
#define L2E 1.4426950408889634f
#define EXP2F(x) __builtin_amdgcn_exp2f(x)

__global__ void setup_kernel(const float* __restrict__ delta,
                             const float* __restrict__ beta,
                             const float* __restrict__ phi,
                             const float* __restrict__ mo,
                             float* __restrict__ ws,
                             float* __restrict__ out) {
    const int g = threadIdx.x;
    if (g == 0) out[0] = 0.0f;   // deterministic re-init every call
    if (g >= NG) return;

    // ln(k!) for k=0..19 (float precision ample: abs threshold ~1.9e6)
    const float lnfact[20] = {
        0.0f, 0.0f, 0.69314718f, 1.79175947f, 3.17805383f,
        4.78749174f, 6.57925121f, 8.52516132f, 10.60460286f, 12.80182744f,
        15.10441253f, 17.50230781f, 19.98721446f, 22.55216381f, 25.19122114f,
        27.89927134f, 30.67186007f, 33.50507341f, 36.39544517f, 39.33988415f};

    float* gtab  = ws + GTAB_OFF;
    float* mdemd = ws + MDEMD_OFF;
    float* lgtab = ws + LGTAB_OFF;

    float ph = fminf(fmaxf(phi[g], 1.0f), 100.0f);
    float plp = ph * __logf(ph);

    unsigned mask = 0u;
#pragma unroll
    for (int t = 0; t < NT; ++t) {
        float m = mo[g * NT + t];
        if (m != 0.0f) mask |= (1u << t);
        float md = m * delta[g * NT + t];
        mdemd[g * 32 + 2 * t]     = md;
        mdemd[g * 32 + 2 * t + 1] = __expf(md);
    }

    gtab[g * 8 + 0] = beta[0 * NG + g];
    gtab[g * 8 + 1] = beta[1 * NG + g];
    gtab[g * 8 + 2] = beta[2 * NG + g];
    gtab[g * 8 + 3] = beta[3 * NG + g];
    gtab[g * 8 + 4] = ph;
    gtab[g * 8 + 5] = __uint_as_float(mask);
    gtab[g * 8 + 6] = 0.0f;
    gtab[g * 8 + 7] = 0.0f;

    // lgtab[k] = sum_{j<k} log(phi+j) - ln(k!) + phi*ln(phi)
    float accn = 0.0f;
    lgtab[g * 20 + 0] = plp;
#pragma unroll
    for (int k = 1; k < 20; ++k) {
        accn += __logf(ph + (float)(k - 1));
        lgtab[g * 20 + k] = accn - lnfact[k] + plp;
    }
}

// Single-phase: block = 64 samples x 128 genes, 8 waves x 16 genes each.
// mo=0 types share one log2(c+phi) per (s,g) (hoisted into hacc); only
// mo=1 types (wave-uniform scalar-branch gated) do per-type work.
__global__ __launch_bounds__(512) void nb_main(const float* __restrict__ expr,
                                               const float* __restrict__ cov,
                                               const float* __restrict__ sfv,
                                               const float* __restrict__ ws,
                                               float* __restrict__ out,
                                               int ns) {
    __shared__ float s_tab[TAB_FLOATS];          // 30.7 KB total LDS

    const int tid = threadIdx.x;
#pragma unroll
    for (int i = 0; i < 4; ++i) {
        int idx = tid + i * 512;
        if (idx < TAB_FLOATS / 4)
            *(float4*)&s_tab[idx * 4] = *(const float4*)(ws + idx * 4);
    }
    __syncthreads();

    const float* __restrict__ s_gt = s_tab + GTAB_OFF;    // [128][8]
    const float* __restrict__ s_md = s_tab + MDEMD_OFF;   // [128][16][2]
    const float* __restrict__ s_lg = s_tab + LGTAB_OFF;   // [128][20]

    const int lane = tid & 63;
    const int q = __builtin_amdgcn_readfirstlane(tid >> 6);  // wave id 0..7
    const int s = blockIdx.x * 64 + lane;
    const bool valid = (s < ns);

    float acc[NT];
#pragma unroll
    for (int t = 0; t < NT; ++t) acc[t] = 0.0f;
    float hacc = 0.0f;

    float4 cv = make_float4(0.f, 0.f, 0.f, 0.f);
    float sf = 1.0f;
    if (valid) {
        cv = *reinterpret_cast<const float4*>(cov + (size_t)s * 4);
        sf = sfv[s];
    }
    const float lsf  = __logf(sf);
    const float lsf2 = lsf * L2E;

    const int g0 = q * 16;   // wave-uniform gene strip (16 genes)

    for (int g4 = 0; g4 < 4; ++g4) {
        float4 kv = make_float4(0.f, 0.f, 0.f, 0.f);
        if (valid)
            kv = *reinterpret_cast<const float4*>(expr + (size_t)s * NG + g0 + g4 * 4);
        float kfv[4] = {kv.x, kv.y, kv.z, kv.w};
#pragma unroll
        for (int j = 0; j < 4; ++j) {
            const int g = g0 + g4 * 4 + j;
            const float b0 = s_gt[g * 8 + 0];
            const float b1 = s_gt[g * 8 + 1];
            const float b2 = s_gt[g * 8 + 2];
            const float b3 = s_gt[g * 8 + 3];
            const float ph = s_gt[g * 8 + 4];
            const unsigned smask =
                __builtin_amdgcn_readfirstlane(__float_as_uint(s_gt[g * 8 + 5]));

            float e = fmaf(b3, cv.w, fmaf(b2, cv.z, fmaf(b1, cv.y, b0 * cv.x)));
            float c = EXP2F(fmaf(e, L2E, lsf2));           // sf * exp(e)
            float kf = kfv[j];
            float lg = s_lg[g * 20 + (int)kf];             // per-lane gather
            float nkp2 = -(kf + ph) * LN2;
            float l20 = __log2f(c + ph);                   // mo=0 shared log
            float n20 = nkp2 * l20;
            // type-independent: k*(lsf+e) + lg + nkp2*l20 (covers all 16 types)
            hacc += fmaf(kf, lsf + e, lg) + n20;
            const float* __restrict__ mp = s_md + g * 32;
#pragma unroll
            for (int t = 0; t < NT; ++t) {
                if (smask & (1u << t)) {                   // wave-uniform branch
                    float md  = mp[2 * t];                 // ds_read_b64
                    float emd = mp[2 * t + 1];
                    float v = fmaf(c, emd, ph);            // mu + phi
                    // replace n20 (already in hacc) by nkp2*log2(v), add k*md
                    acc[t] = fmaf(nkp2, __log2f(v), fmaf(kf, md, acc[t]) - n20);
                }
            }
        }
    }
#pragma unroll
    for (int t = 0; t < NT; ++t) acc[t] += hacc;

    // ---- tree reduction 8 -> 4 -> 2 -> 1 through LDS aliased onto s_tab ----
    float (*red)[64][17] = (float (*)[64][17])s_tab;   // 4*64*17 = 4352 <= 7680
    __syncthreads();                                   // tables dead from here

    if (q >= 4) {
#pragma unroll
        for (int t = 0; t < NT; ++t) red[q - 4][lane][t] = acc[t];
    }
    __syncthreads();
    if (q < 4) {
#pragma unroll
        for (int t = 0; t < NT; ++t) acc[t] += red[q][lane][t];
    }
    __syncthreads();
    if (q == 2 || q == 3) {
#pragma unroll
        for (int t = 0; t < NT; ++t) red[q - 2][lane][t] = acc[t];
    }
    __syncthreads();
    if (q < 2) {
#pragma unroll
        for (int t = 0; t < NT; ++t) acc[t] += red[q][lane][t];
    }
    __syncthreads();
    if (q == 1) {
#pragma unroll
        for (int t = 0; t < NT; ++t) red[0][lane][t] = acc[t];
    }
    __syncthreads();
    if (q == 0) {
        float m = -1e30f;
#pragma unroll
        for (int t = 0; t < NT; ++t) {
            acc[t] += red[0][lane][t];
            m = fmaxf(m, acc[t]);
        }
        float sum = 0.0f;
#pragma unroll
        for (int t = 0; t < NT; ++t) sum += __expf(acc[t] - m);
        float lp = m + __logf(sum);
        if (!valid) lp = 0.0f;
#pragma unroll
        for (int off = 32; off > 0; off >>= 1) lp += __shfl_down(lp, off);
        if (lane == 0) atomicAdd(out, lp);
    }
}

extern "C" void kernel_launch(void* const* d_in, const int* in_sizes, int n_in,
                              void* d_out, int out_size, void* d_ws, size_t ws_size,
                              hipStream_t stream) {
    const float* delta = (const float*)d_in[0];
    const float* beta  = (const float*)d_in[1];
    const float* phi   = (const float*)d_in[2];
    const float* expr  = (const float*)d_in[3];
    const float* cov   = (const float*)d_in[4];
    const float* sf    = (const float*)d_in[5];
    const float* mo    = (const float*)d_in[6];
    float* out = (float*)d_out;
    float* ws  = (float*)d_ws;
    const int ns = in_sizes[5];

    setup_kernel<<<1, 128, 0, stream>>>(delta, beta, phi, mo, ws, out);

    const int tiles = (ns + 63) / 64;
    nb_main<<<tiles, 512, 0, stream>>>(expr, cov, sf, ws, out, ns);
}